// Round 3
// baseline (1292.829 us; speedup 1.0000x reference)
//
#include <hip/hip_runtime.h>
#include <math.h>

// Problem constants
#define BB 16
#define TT 2000
#define CC 1536
#define NH 8
#define DD 192
#define QQ 256
#define AA 192

// ws layout (float offsets)
#define WS_PSUM   0u               // [8][16][1536] partial sums over t-chunks
#define WS_PSQ    196608u          // [8][16][1536]
#define WS_CVEC   393216u          // [16][8][384] interleaved mean/std
#define WS_HCK    442368u          // [16*8][256] head_ck
#define WS_CKDOT  475136u          // [128] sum_q head_ck*vck
#define WS_HCQ    475264u          // [16*8][256][192] head_cq
#define WS_PART   6766720u         // [128][32][192] float4 (m,l,macc,m2acc)
// total ws = 9912448 floats ~= 39.6 MB

// LDS: phase1-2: At[192][68]=52224B + W1c[16][256]=16384B = 68608B
//      phase3-4: khat[64][260]=66560B + W2c[16][192]=12288B = 78848B
//      phase5:   S_ld[64][196]=50176B (aliases khat)
#define LDS_BYTES 78848

__device__ __forceinline__ float fast_tanh(float x) {
    // 1 - 2/(e^{2x}+1): monotone, no NaN at +-inf
    return 1.f - 2.f / (__expf(2.f * x) + 1.f);
}
__device__ __forceinline__ float fast_sigmoid(float x) {
    return 1.f / (1.f + __expf(-x));
}

// ---------------- K1: partial mean/sq sums over t-chunks --------------------
// grid 128 = 16 b * 8 tchunk, block 384 (each thread owns a float4 col-group)
__global__ void k_stats(const float* __restrict__ ht, float* __restrict__ ws) {
    int bid = blockIdx.x;
    int tc = bid & 7;
    int b  = bid >> 3;
    int c4 = threadIdx.x * 4;        // 384*4 = 1536
    const float* p = ht + ((size_t)b * TT + (size_t)tc * 250) * CC + c4;
    float4 s  = make_float4(0.f, 0.f, 0.f, 0.f);
    float4 s2 = make_float4(0.f, 0.f, 0.f, 0.f);
    #pragma unroll 5
    for (int i = 0; i < 250; ++i) {
        float4 v = *(const float4*)(p + (size_t)i * CC);
        s.x += v.x; s.y += v.y; s.z += v.z; s.w += v.w;
        s2.x = fmaf(v.x, v.x, s2.x); s2.y = fmaf(v.y, v.y, s2.y);
        s2.z = fmaf(v.z, v.z, s2.z); s2.w = fmaf(v.w, v.w, s2.w);
    }
    *(float4*)(ws + WS_PSUM + (size_t)(tc * BB + b) * CC + c4) = s;
    *(float4*)(ws + WS_PSQ  + (size_t)(tc * BB + b) * CC + c4) = s2;
}

// ---------------- K2: finalize mean/std -> interleaved cvec -----------------
// grid 16 (b), block 384
__global__ void k_finstats(float* __restrict__ ws) {
    int b  = blockIdx.x;
    int c4 = threadIdx.x * 4;
    float4 s  = make_float4(0.f, 0.f, 0.f, 0.f);
    float4 s2 = make_float4(0.f, 0.f, 0.f, 0.f);
    #pragma unroll
    for (int tc = 0; tc < 8; ++tc) {
        float4 a = *(const float4*)(ws + WS_PSUM + (size_t)(tc * BB + b) * CC + c4);
        float4 q = *(const float4*)(ws + WS_PSQ  + (size_t)(tc * BB + b) * CC + c4);
        s.x += a.x; s.y += a.y; s.z += a.z; s.w += a.w;
        s2.x += q.x; s2.y += q.y; s2.z += q.z; s2.w += q.w;
    }
    float mean[4] = {s.x, s.y, s.z, s.w};
    float sq[4]   = {s2.x, s2.y, s2.z, s2.w};
    float sd[4];
    #pragma unroll
    for (int j = 0; j < 4; ++j) {
        float m = mean[j] * (1.f / TT);
        float var = (sq[j] - (float)TT * m * m) * (1.f / (TT - 1));
        mean[j] = m;
        sd[j] = sqrtf(fmaxf(var, 0.f));
    }
    int k = c4 / DD, dd = c4 - k * DD;       // dd multiple of 4
    float* dst = ws + WS_CVEC + (size_t)b * 3072 + k * 384 + 2 * dd;
    *(float4*)(dst)     = make_float4(mean[0], sd[0], mean[1], sd[1]);
    *(float4*)(dst + 4) = make_float4(mean[2], sd[2], mean[3], sd[3]);
}

// ---------------- K3: per-(b,k) contextual key/query prep -------------------
__global__ void k_prep(const float* __restrict__ ukW,  const float* __restrict__ uq1W,
                       const float* __restrict__ uq1b, const float* __restrict__ uq2,
                       const float* __restrict__ query, const float* __restrict__ vhq,
                       const float* __restrict__ vcq,  const float* __restrict__ vck,
                       const float* __restrict__ bncg, const float* __restrict__ bncb,
                       const float* __restrict__ bncm, const float* __restrict__ bncv,
                       float* __restrict__ ws) {
    __shared__ float cv[384];
    __shared__ float cqh[QQ];
    __shared__ float cq2s[AA];
    __shared__ float red[256];
    int bid = blockIdx.x;            // 128 = 16 b * 8 k
    int b = bid >> 3, k = bid & 7;
    int tid = threadIdx.x;

    for (int i = tid; i < 384; i += 256)
        cv[i] = ws[WS_CVEC + (size_t)b * 3072 + k * 384 + i];
    __syncthreads();

    int q = tid;  // 256 threads == Q
    // head_ck
    const float* up = ukW + (size_t)k * 384 * QQ;
    float hck = 0.f;
    for (int l = 0; l < 384; ++l) hck = fmaf(cv[l], up[l * QQ + q], hck);
    ws[WS_HCK + (size_t)(b * NH + k) * QQ + q] = hck;

    // cq1 -> relu -> BN -> tanh
    const float* u1 = uq1W + (size_t)k * 384 * QQ;
    float cq = uq1b[k * QQ + q];
    for (int l = 0; l < 384; ++l) cq = fmaf(cv[l], u1[l * QQ + q], cq);
    cq = fmaxf(cq, 0.f);
    float sc = bncg[q] * rsqrtf(bncv[q] + 1e-5f);
    cq = fast_tanh(fmaf(cq - bncm[q], sc, bncb[q]));
    cqh[q] = cq;

    // ckdot = sum_q head_ck * vck
    red[tid] = hck * vck[k * QQ + q];
    __syncthreads();
    #pragma unroll
    for (int off = 128; off > 0; off >>= 1) {
        if (tid < off) red[tid] += red[tid + off];
        __syncthreads();
    }
    if (tid == 0) ws[WS_CKDOT + b * NH + k] = red[0];
    __syncthreads();

    // cq2[a] = sum_m cqh[m] * u_q2[k,m,a]
    float c2 = 0.f;
    if (tid < AA) {
        const float* u2 = uq2 + (size_t)k * QQ * AA + tid;
        for (int m = 0; m < QQ; ++m) c2 = fmaf(cqh[m], u2[m * AA], c2);
        cq2s[tid] = c2;
    }

    // lam_q = sigmoid( sum_{q,a} query*vhq + sum_{a,q} cq2*vcq )
    float part = 0.f;
    for (int idx = tid; idx < QQ * AA; idx += 256) {
        int qq = idx / AA, aa = idx - qq * AA;
        part = fmaf(query[(size_t)k * QQ * AA + idx],
                    vhq[(size_t)k * AA * QQ + aa * QQ + qq], part);
    }
    if (tid < AA) {
        const float* vq = vcq + (size_t)k * AA * QQ + (size_t)tid * QQ;
        float w = 0.f;
        for (int qx = 0; qx < QQ; ++qx) w += vq[qx];
        part = fmaf(c2, w, part);
    }
    red[tid] = part;
    __syncthreads();
    #pragma unroll
    for (int off = 128; off > 0; off >>= 1) {
        if (tid < off) red[tid] += red[tid + off];
        __syncthreads();
    }
    float lq = fast_sigmoid(red[0]);

    // head_cq[b,k,q,a] = (1-lq)*query + lq*cq2[a]
    float* hcq = ws + WS_HCQ + (size_t)(b * NH + k) * QQ * AA;
    const float* qr = query + (size_t)k * QQ * AA;
    for (int pos = tid; pos < QQ * AA; pos += 256) {
        int aa = pos % AA;
        hcq[pos] = (1.f - lq) * qr[pos] + lq * cq2s[aa];
    }
}

// ---------------- K4: fused GEMM1 -> gate/BN/tanh -> GEMM2 -> online softmax
__global__ __launch_bounds__(256, 2) void k_main(
        const float* __restrict__ ht,   const float* __restrict__ kpW,
        const float* __restrict__ kpb,  const float* __restrict__ vhk,
        const float* __restrict__ qb_,  const float* __restrict__ bnkg,
        const float* __restrict__ bnkb, const float* __restrict__ bnkm,
        const float* __restrict__ bnkv, float* __restrict__ ws) {
    extern __shared__ float lds[];
    float* At   = lds;            // [192][68] transposed A-tile (phase 1-2)
    float* W1c  = lds + 13056;    // [16][256] k_proj_W chunk    (phase 2)
    float* khat = lds;            // [64][260] aliases At+W1c    (phase 3-4)
    float* W2c  = lds + 16640;    // [16][192] head_cq chunk     (phase 4)
    float* S_ld = lds;            // [64][196] scores            (phase 5, aliases khat)

    int bid = blockIdx.x;         // 4096 = (16*8) bk * 32 tiles
    int bk = bid >> 5, tile = bid & 31;
    int b = bk >> 3, k = bk & 7;
    int t0 = tile * 64;
    int tid = threadIdx.x;
    int tq = tid & 31, tt = tid >> 5;
    int nv = min(64, TT - t0);
    const int q0 = tq * 4, q1 = 128 + tq * 4;   // per-thread q columns (j<4 / j>=4)

    // ---- Phase 1: load + transpose A-tile -------------------------------
    {
        const float* src = ht + ((size_t)b * TT + t0) * CC + k * DD;
        for (int i = tid; i < 64 * 48; i += 256) {
            int row = i / 48, c4 = (i - row * 48) * 4;
            float4 v = make_float4(0.f, 0.f, 0.f, 0.f);
            if (row < nv) v = *(const float4*)(src + (size_t)row * CC + c4);
            At[(c4 + 0) * 68 + row] = v.x;
            At[(c4 + 1) * 68 + row] = v.y;
            At[(c4 + 2) * 68 + row] = v.z;
            At[(c4 + 3) * 68 + row] = v.w;
        }
    }

    // ---- Phase 2: GEMM1  acc[i][j] = sum_d A[t][d] * W1[d][q] -----------
    // W1 chunk register-prefetch: issue chunk kc+1's global loads before the
    // barrier so L2 latency hides under chunk kc's 2048-FMA compute (G15/T14).
    float acc[8][8];
    #pragma unroll
    for (int i = 0; i < 8; ++i)
        #pragma unroll
        for (int j = 0; j < 8; ++j) acc[i][j] = 0.f;

    const float* wsrc = kpW + (size_t)k * DD * QQ;
    const int w1r_r  = tid >> 6;                 // +4 per u  (16 rows / 4 u-steps)
    const int w1c4   = (tid & 63) * 4;
    float4 w1r[4];
    #pragma unroll
    for (int u = 0; u < 4; ++u)
        w1r[u] = *(const float4*)(wsrc + (size_t)(u * 4 + w1r_r) * QQ + w1c4);

    __syncthreads();   // At visible (also orders nothing-yet on W1c)

    for (int kc = 0; kc < 12; ++kc) {
        #pragma unroll
        for (int u = 0; u < 4; ++u)
            *(float4*)(W1c + (u * 4 + w1r_r) * QQ + w1c4) = w1r[u];
        if (kc < 11) {
            #pragma unroll
            for (int u = 0; u < 4; ++u)
                w1r[u] = *(const float4*)(wsrc + (size_t)((kc + 1) * 16 + u * 4 + w1r_r) * QQ + w1c4);
        }
        __syncthreads();
        #pragma unroll
        for (int kk = 0; kk < 16; ++kk) {
            int d = kc * 16 + kk;
            float4 a0 = *(const float4*)(At + d * 68 + tt * 8);
            float4 a1 = *(const float4*)(At + d * 68 + tt * 8 + 4);
            float4 b0 = *(const float4*)(W1c + kk * QQ + q0);
            float4 b1 = *(const float4*)(W1c + kk * QQ + q1);
            float af[8] = {a0.x, a0.y, a0.z, a0.w, a1.x, a1.y, a1.z, a1.w};
            float bf[8] = {b0.x, b0.y, b0.z, b0.w, b1.x, b1.y, b1.z, b1.w};
            #pragma unroll
            for (int i = 0; i < 8; ++i)
                #pragma unroll
                for (int j = 0; j < 8; ++j)
                    acc[i][j] = fmaf(af[i], bf[j], acc[i][j]);
        }
        __syncthreads();
    }

    // ---- Phase 3: lam_k, gate, bias, relu, BN, tanh -> khat in LDS ------
    float vhk_r[8], hck_r[8], kb_r[8], bsc[8], bsh[8];
    #pragma unroll
    for (int j = 0; j < 8; ++j) {
        int q = (j < 4) ? (q0 + j) : (q1 + j - 4);
        vhk_r[j] = vhk[k * QQ + q];
        hck_r[j] = ws[WS_HCK + (size_t)bk * QQ + q];
        kb_r[j]  = kpb[k * QQ + q];
        float s  = bnkg[q] * rsqrtf(bnkv[q] + 1e-5f);
        bsc[j]   = s;
        bsh[j]   = bnkb[q] - bnkm[q] * s;
    }
    float ckd = ws[WS_CKDOT + bk];

    #pragma unroll
    for (int i = 0; i < 8; ++i) {
        float rd = 0.f;
        #pragma unroll
        for (int j = 0; j < 8; ++j) rd = fmaf(acc[i][j], vhk_r[j], rd);
        #pragma unroll
        for (int off = 16; off > 0; off >>= 1) rd += __shfl_xor(rd, off, 32);
        float lam = fast_sigmoid(rd + ckd);
        #pragma unroll
        for (int j = 0; j < 8; ++j) {
            float hk = (1.f - lam) * acc[i][j] + lam * hck_r[j];
            float x  = fmaxf(hk + kb_r[j], 0.f);
            acc[i][j] = fast_tanh(fmaf(x, bsc[j], bsh[j]));
        }
    }
    // khat aliases At/W1c: all reads of those finished at last __syncthreads
    #pragma unroll
    for (int i = 0; i < 8; ++i) {
        int t = tt * 8 + i;
        *(float4*)(khat + t * 260 + q0) =
            make_float4(acc[i][0], acc[i][1], acc[i][2], acc[i][3]);
        *(float4*)(khat + t * 260 + q1) =
            make_float4(acc[i][4], acc[i][5], acc[i][6], acc[i][7]);
    }

    // ---- Phase 4: GEMM2, 16x16 thread grid, 4t x 12a register tile ------
    // thread (tt2, ta2): t rows tt2*4..+3, a cols ta2*12..+11
    const int ta2 = tid & 15, tt2 = tid >> 4;
    const int a0 = ta2 * 12;
    float acc2[4][12];
    #pragma unroll
    for (int i = 0; i < 4; ++i)
        #pragma unroll
        for (int j = 0; j < 12; ++j) acc2[i][j] = 0.f;

    // W2 chunk register-prefetch (3 float4 per thread per 16-row chunk)
    const float* hcq = ws + WS_HCQ + (size_t)bk * QQ * AA;
    int w2i_r[3], w2i_c[3];
    float4 w2r[3];
    #pragma unroll
    for (int u = 0; u < 3; ++u) {
        int i = tid + u * 256;
        w2i_r[u] = i / 48;
        w2i_c[u] = (i - w2i_r[u] * 48) * 4;
        w2r[u] = *(const float4*)(hcq + (size_t)w2i_r[u] * AA + w2i_c[u]);
    }

    __syncthreads();   // khat visible

    for (int qc = 0; qc < 16; ++qc) {
        #pragma unroll
        for (int u = 0; u < 3; ++u)
            *(float4*)(W2c + w2i_r[u] * AA + w2i_c[u]) = w2r[u];
        if (qc < 15) {
            #pragma unroll
            for (int u = 0; u < 3; ++u)
                w2r[u] = *(const float4*)(hcq + (size_t)((qc + 1) * 16 + w2i_r[u]) * AA + w2i_c[u]);
        }
        __syncthreads();
        #pragma unroll
        for (int kq = 0; kq < 16; kq += 4) {
            // khat rows: 4 t, 4 consecutive q each (pad 260 -> banks rotate by 4/row)
            float kfa[4][4];
            #pragma unroll
            for (int i = 0; i < 4; ++i) {
                float4 v = *(const float4*)(khat + (size_t)(tt2 * 4 + i) * 260 + qc * 16 + kq);
                kfa[i][0] = v.x; kfa[i][1] = v.y; kfa[i][2] = v.z; kfa[i][3] = v.w;
            }
            #pragma unroll
            for (int qq = 0; qq < 4; ++qq) {
                float4 b0 = *(const float4*)(W2c + (kq + qq) * AA + a0);
                float4 b1 = *(const float4*)(W2c + (kq + qq) * AA + a0 + 4);
                float4 b2 = *(const float4*)(W2c + (kq + qq) * AA + a0 + 8);
                float bf[12] = {b0.x, b0.y, b0.z, b0.w,
                                b1.x, b1.y, b1.z, b1.w,
                                b2.x, b2.y, b2.z, b2.w};
                #pragma unroll
                for (int i = 0; i < 4; ++i)
                    #pragma unroll
                    for (int j = 0; j < 12; ++j)
                        acc2[i][j] = fmaf(kfa[i][qq], bf[j], acc2[i][j]);
            }
        }
        __syncthreads();
    }

    // ---- write scores to LDS (aliases dead khat; synced above) ----------
    #pragma unroll
    for (int i = 0; i < 4; ++i) {
        int t = tt2 * 4 + i;
        *(float4*)(S_ld + t * 196 + a0)     = make_float4(acc2[i][0], acc2[i][1], acc2[i][2], acc2[i][3]);
        *(float4*)(S_ld + t * 196 + a0 + 4) = make_float4(acc2[i][4], acc2[i][5], acc2[i][6], acc2[i][7]);
        *(float4*)(S_ld + t * 196 + a0 + 8) = make_float4(acc2[i][8], acc2[i][9], acc2[i][10], acc2[i][11]);
    }
    __syncthreads();

    // ---- Phase 5: online softmax over t, weighted value moments ---------
    if (tid < AA) {
        int a = tid;
        float qb = qb_[k * AA + a];
        const float* vp = ht + ((size_t)b * TT + t0) * CC + k * DD + a;
        float m = -3.0e38f, l = 0.f, mac = 0.f, m2 = 0.f;
        if (nv == 64) {
            #pragma unroll
            for (int t = 0; t < 64; ++t) {
                float s  = fmaf(S_ld[t * 196 + a], 0.0625f, qb);  // /sqrt(256) + q_b
                float v  = vp[(size_t)t * CC];
                float mn = fmaxf(m, s);
                float rs = __expf(m - mn);
                float e  = __expf(s - mn);
                l   = fmaf(l,   rs, e);
                mac = fmaf(mac, rs, e * v);
                m2  = fmaf(m2,  rs, e * v * v);
                m = mn;
            }
        } else {
            for (int t = 0; t < nv; ++t) {
                float s  = fmaf(S_ld[t * 196 + a], 0.0625f, qb);
                float v  = vp[(size_t)t * CC];
                float mn = fmaxf(m, s);
                float rs = __expf(m - mn);
                float e  = __expf(s - mn);
                l   = fmaf(l,   rs, e);
                mac = fmaf(mac, rs, e * v);
                m2  = fmaf(m2,  rs, e * v * v);
                m = mn;
            }
        }
        float4 o = make_float4(m, l, mac, m2);
        ((float4*)(ws + WS_PART))[(size_t)(bk * 32 + tile) * AA + a] = o;
    }
}

// ---------------- K5: merge tile partials, emit mu / rh ---------------------
__global__ void k_merge(const float* __restrict__ ws, float* __restrict__ out) {
    int bk = blockIdx.x;             // 128
    int b = bk >> 3, k = bk & 7;
    int a = threadIdx.x;             // 192
    const float4* part = (const float4*)(ws + WS_PART) + (size_t)bk * 32 * AA + a;
    float M = -3.0e38f;
    #pragma unroll 4
    for (int ti = 0; ti < 32; ++ti) M = fmaxf(M, part[(size_t)ti * AA].x);
    float L = 0.f, MU = 0.f, M2 = 0.f;
    #pragma unroll 4
    for (int ti = 0; ti < 32; ++ti) {
        float4 p = part[(size_t)ti * AA];
        float sc = __expf(p.x - M);
        L  = fmaf(p.y, sc, L);
        MU = fmaf(p.z, sc, MU);
        M2 = fmaf(p.w, sc, M2);
    }
    MU /= L;
    M2 /= L;
    float rh = sqrtf(fmaxf(M2 - MU * MU, 1e-9f));
    out[(size_t)b * 3072 + k * DD + a]      = MU;
    out[(size_t)b * 3072 + CC + k * DD + a] = rh;
}

// ---------------------------------------------------------------------------
extern "C" void kernel_launch(void* const* d_in, const int* in_sizes, int n_in,
                              void* d_out, int out_size, void* d_ws, size_t ws_size,
                              hipStream_t stream) {
    const float* ht    = (const float*)d_in[0];
    const float* kpW   = (const float*)d_in[1];
    const float* query = (const float*)d_in[2];
    const float* ukW   = (const float*)d_in[3];
    const float* uq1W  = (const float*)d_in[4];
    const float* uq2   = (const float*)d_in[5];
    const float* vhq   = (const float*)d_in[6];
    const float* vhk   = (const float*)d_in[7];
    const float* vcq   = (const float*)d_in[8];
    const float* vck   = (const float*)d_in[9];
    const float* kpb   = (const float*)d_in[10];
    const float* qb    = (const float*)d_in[11];
    const float* uq1b  = (const float*)d_in[12];
    const float* bncg  = (const float*)d_in[13];
    const float* bncb  = (const float*)d_in[14];
    const float* bncm  = (const float*)d_in[15];
    const float* bncv  = (const float*)d_in[16];
    const float* bnkg  = (const float*)d_in[17];
    const float* bnkb  = (const float*)d_in[18];
    const float* bnkm  = (const float*)d_in[19];
    const float* bnkv  = (const float*)d_in[20];
    float* ws  = (float*)d_ws;
    float* out = (float*)d_out;

    hipFuncSetAttribute(reinterpret_cast<const void*>(k_main),
                        hipFuncAttributeMaxDynamicSharedMemorySize, LDS_BYTES);

    k_stats   <<<128, 384, 0, stream>>>(ht, ws);
    k_finstats<<<16, 384, 0, stream>>>(ws);
    k_prep    <<<128, 256, 0, stream>>>(ukW, uq1W, uq1b, uq2, query, vhq, vcq, vck,
                                        bncg, bncb, bncm, bncv, ws);
    k_main    <<<4096, 256, LDS_BYTES, stream>>>(ht, kpW, kpb, vhk, qb,
                                                 bnkg, bnkb, bnkm, bnkv, ws);
    k_merge   <<<128, 192, 0, stream>>>(ws, out);
}

// Round 5
// 675.300 us; speedup vs baseline: 1.9145x; 1.9145x over previous
//
#include <hip/hip_runtime.h>
#include <math.h>

// Problem constants
#define BB 16
#define TT 2000
#define CC 1536
#define NH 8
#define DD 192
#define QQ 256
#define AA 192

// ws layout (float offsets)
#define WS_PSUM   0u               // [25tc][16b][1536]
#define WS_PSQ    614400u          // [25tc][16b][1536]
#define WS_CVEC   1228800u         // [16b][8k][384] interleaved mean/std
#define WS_HCK    1277952u         // [128bk][256] head_ck (fp32)
#define WS_CKDOT  1310720u         // [128] sum_q head_ck*vck
#define WS_W1T    1310848u         // bf16 [8k][256q][192d]  (W1 transposed)
#define WS_HCQT   1507456u         // bf16 [128bk][192a][256q] (head_cq transposed)
#define WS_PART   4653184u         // [128bk][32tile][192a] float4 (m,l,macc,m2acc)
// total = 7798912 floats ~= 31.2 MB

// k_main LDS (bytes):
//   khat:   [0,32768)      [64t][256q] bf16, row 512B, XOR ((t&7)<<4)
//   tbl4:   [32768,36864)  float4[256] = (hck, kpb, bn_scale, bn_shift)
//   lamred: [36864,37888)  float[4][64] cross-wave lam partials (row0 reused as lam table)
//   Ab:     [37888,54272)  [64t][96d used] bf16, row 256B, XOR ((t&7)<<4)
//   S:      [0,50176)      [64][196] f32 (aliases khat+tbl+lamred+Ab-part; all dead by dump)
#define LDS_BYTES 54272            // x3 blocks = 162816 <= 163840 (3 blocks/CU)

typedef short bf16x8 __attribute__((ext_vector_type(8)));
typedef float f32x4  __attribute__((ext_vector_type(4)));

__device__ __forceinline__ float fast_tanh(float x) {
    return 1.f - 2.f / (__expf(2.f * x) + 1.f);
}
__device__ __forceinline__ float fast_sigmoid(float x) {
    return 1.f / (1.f + __expf(-x));
}
__device__ __forceinline__ short f2bf(float x) {   // RNE f32 -> bf16
    unsigned u = __builtin_bit_cast(unsigned, x);
    u += 0x7FFFu + ((u >> 16) & 1u);
    return (short)(u >> 16);
}

// ---------------- K1: partial mean/sq sums over t-chunks --------------------
// grid 400 = 16 b * 25 tchunk(80 rows), block 384
__global__ void k_stats(const float* __restrict__ ht, float* __restrict__ ws) {
    int bid = blockIdx.x;
    int tc = bid % 25;
    int b  = bid / 25;
    int c4 = threadIdx.x * 4;
    const float* p = ht + ((size_t)b * TT + (size_t)tc * 80) * CC + c4;
    float4 s  = make_float4(0.f, 0.f, 0.f, 0.f);
    float4 s2 = make_float4(0.f, 0.f, 0.f, 0.f);
    #pragma unroll 8
    for (int i = 0; i < 80; ++i) {
        float4 v = *(const float4*)(p + (size_t)i * CC);
        s.x += v.x; s.y += v.y; s.z += v.z; s.w += v.w;
        s2.x = fmaf(v.x, v.x, s2.x); s2.y = fmaf(v.y, v.y, s2.y);
        s2.z = fmaf(v.z, v.z, s2.z); s2.w = fmaf(v.w, v.w, s2.w);
    }
    *(float4*)(ws + WS_PSUM + (size_t)(tc * BB + b) * CC + c4) = s;
    *(float4*)(ws + WS_PSQ  + (size_t)(tc * BB + b) * CC + c4) = s2;
}

// ---------------- K2: finalize mean/std -> interleaved cvec -----------------
__global__ void k_finstats(float* __restrict__ ws) {
    int b  = blockIdx.x;
    int c4 = threadIdx.x * 4;
    float4 s  = make_float4(0.f, 0.f, 0.f, 0.f);
    float4 s2 = make_float4(0.f, 0.f, 0.f, 0.f);
    for (int tc = 0; tc < 25; ++tc) {
        float4 a = *(const float4*)(ws + WS_PSUM + (size_t)(tc * BB + b) * CC + c4);
        float4 q = *(const float4*)(ws + WS_PSQ  + (size_t)(tc * BB + b) * CC + c4);
        s.x += a.x; s.y += a.y; s.z += a.z; s.w += a.w;
        s2.x += q.x; s2.y += q.y; s2.z += q.z; s2.w += q.w;
    }
    float mean[4] = {s.x, s.y, s.z, s.w};
    float sq[4]   = {s2.x, s2.y, s2.z, s2.w};
    float sd[4];
    #pragma unroll
    for (int j = 0; j < 4; ++j) {
        float m = mean[j] * (1.f / TT);
        float var = (sq[j] - (float)TT * m * m) * (1.f / (TT - 1));
        mean[j] = m;
        sd[j] = sqrtf(fmaxf(var, 0.f));
    }
    int k = c4 / DD, dd = c4 - k * DD;
    float* dst = ws + WS_CVEC + (size_t)b * 3072 + k * 384 + 2 * dd;
    *(float4*)(dst)     = make_float4(mean[0], sd[0], mean[1], sd[1]);
    *(float4*)(dst + 4) = make_float4(mean[2], sd[2], mean[3], sd[3]);
}

// ---------------- K2b: k_proj_W fp32 [k][d][q] -> bf16 [k][q][d] ------------
__global__ void k_convw(const float* __restrict__ kpW, float* __restrict__ ws) {
    int k  = blockIdx.x / 3, dc = blockIdx.x % 3;
    int q  = threadIdx.x;
    short* dst = (short*)(ws + WS_W1T) + ((size_t)k * QQ + q) * DD;
    const float* src = kpW + (size_t)k * DD * QQ + q;
    #pragma unroll 4
    for (int u = 0; u < 16; ++u) {
        int d = dc * 64 + u * 4;
        short4 s4;
        s4.x = f2bf(src[(size_t)(d + 0) * QQ]);
        s4.y = f2bf(src[(size_t)(d + 1) * QQ]);
        s4.z = f2bf(src[(size_t)(d + 2) * QQ]);
        s4.w = f2bf(src[(size_t)(d + 3) * QQ]);
        *(short4*)(dst + d) = s4;
    }
}

// ---------------- K3: per-(b,k) contextual key/query prep -------------------
__global__ void k_prep(const float* __restrict__ ukW,  const float* __restrict__ uq1W,
                       const float* __restrict__ uq1b, const float* __restrict__ uq2,
                       const float* __restrict__ query, const float* __restrict__ vhq,
                       const float* __restrict__ vcq,  const float* __restrict__ vck,
                       const float* __restrict__ bncg, const float* __restrict__ bncb,
                       const float* __restrict__ bncm, const float* __restrict__ bncv,
                       float* __restrict__ ws) {
    __shared__ float cv[384];
    __shared__ float cqh[QQ];
    __shared__ float cq2s[AA];
    __shared__ float red[256];
    int bid = blockIdx.x;            // 128 = 16 b * 8 k
    int b = bid >> 3, k = bid & 7;
    int tid = threadIdx.x;

    for (int i = tid; i < 384; i += 256)
        cv[i] = ws[WS_CVEC + (size_t)b * 3072 + k * 384 + i];
    __syncthreads();

    int q = tid;  // 256 threads == Q
    const float* up = ukW + (size_t)k * 384 * QQ;
    float hck = 0.f;
    for (int l = 0; l < 384; ++l) hck = fmaf(cv[l], up[l * QQ + q], hck);
    ws[WS_HCK + (size_t)(b * NH + k) * QQ + q] = hck;

    const float* u1 = uq1W + (size_t)k * 384 * QQ;
    float cq = uq1b[k * QQ + q];
    for (int l = 0; l < 384; ++l) cq = fmaf(cv[l], u1[l * QQ + q], cq);
    cq = fmaxf(cq, 0.f);
    float sc = bncg[q] * rsqrtf(bncv[q] + 1e-5f);
    cq = fast_tanh(fmaf(cq - bncm[q], sc, bncb[q]));
    cqh[q] = cq;

    red[tid] = hck * vck[k * QQ + q];
    __syncthreads();
    #pragma unroll
    for (int off = 128; off > 0; off >>= 1) {
        if (tid < off) red[tid] += red[tid + off];
        __syncthreads();
    }
    if (tid == 0) ws[WS_CKDOT + b * NH + k] = red[0];
    __syncthreads();

    float c2 = 0.f;
    if (tid < AA) {
        const float* u2 = uq2 + (size_t)k * QQ * AA + tid;
        for (int m = 0; m < QQ; ++m) c2 = fmaf(cqh[m], u2[m * AA], c2);
        cq2s[tid] = c2;
    }

    float part = 0.f;
    for (int idx = tid; idx < QQ * AA; idx += 256) {
        int qq = idx / AA, aa = idx - qq * AA;
        part = fmaf(query[(size_t)k * QQ * AA + idx],
                    vhq[(size_t)k * AA * QQ + aa * QQ + qq], part);
    }
    if (tid < AA) {
        const float* vq = vcq + (size_t)k * AA * QQ + (size_t)tid * QQ;
        float w = 0.f;
        for (int qx = 0; qx < QQ; ++qx) w += vq[qx];
        part = fmaf(c2, w, part);
    }
    red[tid] = part;
    __syncthreads();
    #pragma unroll
    for (int off = 128; off > 0; off >>= 1) {
        if (tid < off) red[tid] += red[tid + off];
        __syncthreads();
    }
    float lq = fast_sigmoid(red[0]);

    // head_cq -> bf16 TRANSPOSED [a][q]
    short* hq = (short*)(ws + WS_HCQT) + (size_t)(b * NH + k) * AA * QQ;
    const float* qr = query + (size_t)k * QQ * AA;
    for (int pos = tid; pos < AA * QQ; pos += 256) {
        int aa = pos >> 8, qq = pos & 255;
        float val = (1.f - lq) * qr[qq * AA + aa] + lq * cq2s[aa];
        hq[pos] = f2bf(val);
    }
}

// ---------------- K4: MFMA GEMM1 -> gate/BN/tanh -> MFMA GEMM2 -> softmax ---
// Column-split waves: GEMM1 wave w owns q in [w*64,(w+1)*64); GEMM2 a in [w*48,...)
__global__ __launch_bounds__(256, 3) void k_main(
        const float* __restrict__ ht,   const float* __restrict__ kpb,
        const float* __restrict__ vhk,  const float* __restrict__ qb_,
        const float* __restrict__ bnkg, const float* __restrict__ bnkb,
        const float* __restrict__ bnkm, const float* __restrict__ bnkv,
        float* __restrict__ ws) {
    extern __shared__ char lds[];
    float4* tbl4   = (float4*)(lds + 32768);   // (hck, kpb, bsc, bsh)
    float*  lamred = (float*)(lds + 36864);    // [4][64]; row0 doubles as lam table
    char*   Ab     = lds + 37888;
    float*  S_ld   = (float*)lds;

    int bid = blockIdx.x;         // 4096 = 128 bk * 32 tiles
    int bk = bid >> 5, tile = bid & 31;
    int b = bk >> 3, k = bk & 7;
    int t0 = tile * 64;
    int tid = threadIdx.x;
    int w  = tid >> 6;            // wave id (column-group owner)
    int l  = tid & 63;
    int lr = l & 15, lg = l >> 4;
    int nv = min(64, TT - t0);

    // ---- param table (per q) -------------------------------------------
    {
        int q = tid;
        float hckv = ws[WS_HCK + (size_t)bk * QQ + q];
        float kbv  = kpb[k * QQ + q];
        float bscv = bnkg[q] * rsqrtf(bnkv[q] + 1e-5f);
        float bshv = bnkb[q] - bnkm[q] * bscv;
        tbl4[q] = make_float4(hckv, kbv, bscv, bshv);
    }
    float ckd = ws[WS_CKDOT + bk];

    // vhk for this lane's 4 owned q-columns (L2-hot, tiny)
    float vv[4];
    #pragma unroll
    for (int cc = 0; cc < 4; ++cc)
        vv[cc] = vhk[k * QQ + w * 64 + cc * 16 + lr];

    // ---- GEMM1: C1[64t][256q] = ht_tile[64][192] x W1[192][256] ---------
    // acc1[tg][cc]: rows tg*16+lg*4+r, col w*64+cc*16+lr
    f32x4 acc1[4][4];
    #pragma unroll
    for (int tg = 0; tg < 4; ++tg)
        #pragma unroll
        for (int cc = 0; cc < 4; ++cc) acc1[tg][cc] = (f32x4){0.f, 0.f, 0.f, 0.f};

    const short* w1s = (const short*)(ws + WS_W1T) + (size_t)k * QQ * DD;
    const int r_ = tid >> 2, cs = tid & 3;   // staging: 4 threads per t-row

    #pragma unroll
    for (int half = 0; half < 2; ++half) {
        __syncthreads();   // Ab region free for this half
        {
            const float* src = ht + ((size_t)b * TT + t0 + r_) * CC + k * DD + half * 96;
            bool ok = (t0 + r_) < TT;
            #pragma unroll
            for (int u = 0; u < 6; ++u) {
                int c4 = cs * 24 + u * 4;
                float4 v = make_float4(0.f, 0.f, 0.f, 0.f);
                if (ok) v = *(const float4*)(src + c4);
                short4 s4;
                s4.x = f2bf(v.x); s4.y = f2bf(v.y); s4.z = f2bf(v.z); s4.w = f2bf(v.w);
                int byte = (r_ << 8) + (c4 << 1);
                byte ^= (r_ & 7) << 4;
                *(short4*)(Ab + byte) = s4;
            }
        }
        __syncthreads();
        // A-frags for ALL 4 t-groups (reused across the wave's 4 c-groups)
        bf16x8 af[4][3];
        #pragma unroll
        for (int tg = 0; tg < 4; ++tg)
            #pragma unroll
            for (int kb = 0; kb < 3; ++kb) {
                int t = tg * 16 + lr;
                int byte = (t << 8) + ((kb * 32 + lg * 8) << 1);
                byte ^= (t & 7) << 4;
                af[tg][kb] = *(const bf16x8*)(Ab + byte);
            }
        #pragma unroll
        for (int cc = 0; cc < 4; ++cc) {
            const short* bq = w1s + (size_t)(w * 64 + cc * 16 + lr) * DD + half * 96 + lg * 8;
            bf16x8 bf0 = *(const bf16x8*)(bq);
            bf16x8 bf1 = *(const bf16x8*)(bq + 32);
            bf16x8 bf2 = *(const bf16x8*)(bq + 64);
            #pragma unroll
            for (int tg = 0; tg < 4; ++tg) {
                acc1[tg][cc] = __builtin_amdgcn_mfma_f32_16x16x32_bf16(af[tg][0], bf0, acc1[tg][cc], 0, 0, 0);
                acc1[tg][cc] = __builtin_amdgcn_mfma_f32_16x16x32_bf16(af[tg][1], bf1, acc1[tg][cc], 0, 0, 0);
                acc1[tg][cc] = __builtin_amdgcn_mfma_f32_16x16x32_bf16(af[tg][2], bf2, acc1[tg][cc], 0, 0, 0);
            }
        }
    }

    // ---- lam_k: cross-wave row-dot reduction ----------------------------
    {
        float rdp[4][4];
        #pragma unroll
        for (int tg = 0; tg < 4; ++tg)
            #pragma unroll
            for (int r = 0; r < 4; ++r) {
                float s = 0.f;
                #pragma unroll
                for (int cc = 0; cc < 4; ++cc) s = fmaf(acc1[tg][cc][r], vv[cc], s);
                #pragma unroll
                for (int off = 1; off < 16; off <<= 1) s += __shfl_xor(s, off);
                rdp[tg][r] = s;
            }
        if (lr == 0) {
            #pragma unroll
            for (int tg = 0; tg < 4; ++tg)
                #pragma unroll
                for (int r = 0; r < 4; ++r)
                    lamred[w * 64 + tg * 16 + lg * 4 + r] = rdp[tg][r];
        }
    }
    __syncthreads();
    if (tid < 64) {   // fold 4 wave-partials -> sigmoid -> lam table (row 0 in place)
        float s = lamred[tid] + lamred[64 + tid] + lamred[128 + tid] + lamred[192 + tid];
        lamred[tid] = fast_sigmoid(s + ckd);
    }
    __syncthreads();

    // ---- Phase 3: gate, bias, relu, BN, tanh -> khat bf16 ---------------
    {
        float lamv[4][4];
        #pragma unroll
        for (int tg = 0; tg < 4; ++tg)
            #pragma unroll
            for (int r = 0; r < 4; ++r)
                lamv[tg][r] = lamred[tg * 16 + lg * 4 + r];
        #pragma unroll
        for (int cc = 0; cc < 4; ++cc) {
            int q = w * 64 + cc * 16 + lr;
            float4 tv = tbl4[q];
            #pragma unroll
            for (int tg = 0; tg < 4; ++tg)
                #pragma unroll
                for (int r = 0; r < 4; ++r) {
                    float lam = lamv[tg][r];
                    float hk = (1.f - lam) * acc1[tg][cc][r] + lam * tv.x;
                    float x  = fmaxf(hk + tv.y, 0.f);
                    float kh = fast_tanh(fmaf(x, tv.z, tv.w));
                    int t = tg * 16 + lg * 4 + r;
                    int byte = (t << 9) + (q << 1);
                    byte ^= (t & 7) << 4;
                    *(short*)(lds + byte) = f2bf(kh);
                }
        }
    }
    __syncthreads();   // khat fully written (cross-wave reads follow)

    // ---- GEMM2: S[64t][192a] = khat[64][256] x hcq[256][192] ------------
    f32x4 acc2[4][3];
    #pragma unroll
    for (int tg = 0; tg < 4; ++tg)
        #pragma unroll
        for (int cc = 0; cc < 3; ++cc) acc2[tg][cc] = (f32x4){0.f, 0.f, 0.f, 0.f};

    const short* hq = (const short*)(ws + WS_HCQT) + (size_t)bk * AA * QQ;
    #pragma unroll
    for (int kb = 0; kb < 8; ++kb) {
        bf16x8 kf[4];
        #pragma unroll
        for (int tg = 0; tg < 4; ++tg) {
            int t = tg * 16 + lr;
            int byte = (t << 9) + ((kb * 32 + lg * 8) << 1);
            byte ^= (t & 7) << 4;
            kf[tg] = *(const bf16x8*)(lds + byte);
        }
        #pragma unroll
        for (int cc = 0; cc < 3; ++cc) {
            const short* ba = hq + (size_t)(w * 48 + cc * 16 + lr) * QQ + kb * 32 + lg * 8;
            bf16x8 bfv = *(const bf16x8*)ba;
            #pragma unroll
            for (int tg = 0; tg < 4; ++tg)
                acc2[tg][cc] = __builtin_amdgcn_mfma_f32_16x16x32_bf16(kf[tg], bfv, acc2[tg][cc], 0, 0, 0);
        }
    }
    __syncthreads();   // khat/tbl/lamred/Ab dead -> S may overwrite

    #pragma unroll
    for (int tg = 0; tg < 4; ++tg)
        #pragma unroll
        for (int cc = 0; cc < 3; ++cc) {
            int a = w * 48 + cc * 16 + lr;
            #pragma unroll
            for (int r = 0; r < 4; ++r)
                S_ld[(tg * 16 + lg * 4 + r) * 196 + a] = acc2[tg][cc][r];
        }
    __syncthreads();

    // ---- Phase 5: softmax accum over t (static max 0; |s|<~1 by tanh bound)
    if (tid < AA) {
        int a = tid;
        float qb = qb_[k * AA + a];
        const float* vp = ht + ((size_t)b * TT + t0) * CC + k * DD + a;
        float lsum = 0.f, mac = 0.f, m2 = 0.f;
        if (nv == 64) {
            #pragma unroll 8
            for (int t = 0; t < 64; ++t) {
                float s = fminf(fmaf(S_ld[t * 196 + a], 0.0625f, qb), 30.f);
                float e = __expf(s);
                float v = vp[(size_t)t * CC];
                float t1 = e * v;
                lsum += e;
                mac  += t1;
                m2    = fmaf(t1, v, m2);
            }
        } else {
            for (int t = 0; t < nv; ++t) {
                float s = fminf(fmaf(S_ld[t * 196 + a], 0.0625f, qb), 30.f);
                float e = __expf(s);
                float v = vp[(size_t)t * CC];
                float t1 = e * v;
                lsum += e;
                mac  += t1;
                m2    = fmaf(t1, v, m2);
            }
        }
        ((float4*)(ws + WS_PART))[(size_t)(bk * 32 + tile) * AA + a] =
            make_float4(0.f, lsum, mac, m2);
    }
}

// ---------------- K5: merge tile partials, emit mu / rh ---------------------
__global__ void k_merge(const float* __restrict__ ws, float* __restrict__ out) {
    int bk = blockIdx.x;             // 128
    int b = bk >> 3, k = bk & 7;
    int a = threadIdx.x;             // 192
    const float4* part = (const float4*)(ws + WS_PART) + (size_t)bk * 32 * AA + a;
    float M = -3.0e38f;
    #pragma unroll 4
    for (int ti = 0; ti < 32; ++ti) M = fmaxf(M, part[(size_t)ti * AA].x);
    float L = 0.f, MU = 0.f, M2 = 0.f;
    #pragma unroll 4
    for (int ti = 0; ti < 32; ++ti) {
        float4 p = part[(size_t)ti * AA];
        float sc = __expf(p.x - M);
        L  = fmaf(p.y, sc, L);
        MU = fmaf(p.z, sc, MU);
        M2 = fmaf(p.w, sc, M2);
    }
    MU /= L;
    M2 /= L;
    float rh = sqrtf(fmaxf(M2 - MU * MU, 1e-9f));
    out[(size_t)b * 3072 + k * DD + a]      = MU;
    out[(size_t)b * 3072 + CC + k * DD + a] = rh;
}

// ---------------------------------------------------------------------------
extern "C" void kernel_launch(void* const* d_in, const int* in_sizes, int n_in,
                              void* d_out, int out_size, void* d_ws, size_t ws_size,
                              hipStream_t stream) {
    const float* ht    = (const float*)d_in[0];
    const float* kpW   = (const float*)d_in[1];
    const float* query = (const float*)d_in[2];
    const float* ukW   = (const float*)d_in[3];
    const float* uq1W  = (const float*)d_in[4];
    const float* uq2   = (const float*)d_in[5];
    const float* vhq   = (const float*)d_in[6];
    const float* vhk   = (const float*)d_in[7];
    const float* vcq   = (const float*)d_in[8];
    const float* vck   = (const float*)d_in[9];
    const float* kpb   = (const float*)d_in[10];
    const float* qb    = (const float*)d_in[11];
    const float* uq1b  = (const float*)d_in[12];
    const float* bncg  = (const float*)d_in[13];
    const float* bncb  = (const float*)d_in[14];
    const float* bncm  = (const float*)d_in[15];
    const float* bncv  = (const float*)d_in[16];
    const float* bnkg  = (const float*)d_in[17];
    const float* bnkb  = (const float*)d_in[18];
    const float* bnkm  = (const float*)d_in[19];
    const float* bnkv  = (const float*)d_in[20];
    float* ws  = (float*)d_ws;
    float* out = (float*)d_out;

    hipFuncSetAttribute(reinterpret_cast<const void*>(k_main),
                        hipFuncAttributeMaxDynamicSharedMemorySize, LDS_BYTES);

    k_stats   <<<400, 384, 0, stream>>>(ht, ws);
    k_finstats<<<16, 384, 0, stream>>>(ws);
    k_convw   <<<24, 256, 0, stream>>>(kpW, ws);
    k_prep    <<<128, 256, 0, stream>>>(ukW, uq1W, uq1b, uq2, query, vhq, vcq, vck,
                                        bncg, bncb, bncm, bncv, ws);
    k_main    <<<4096, 256, LDS_BYTES, stream>>>(ht, kpb, vhk, qb,
                                                 bnkg, bnkb, bnkm, bnkv, ws);
    k_merge   <<<128, 192, 0, stream>>>(ws, out);
}

// Round 8
// 598.810 us; speedup vs baseline: 2.1590x; 1.1277x over previous
//
#include <hip/hip_runtime.h>
#include <math.h>

// Problem constants
#define BB 16
#define TT 2000
#define CC 1536
#define NH 8
#define DD 192
#define QQ 256
#define AA 192

// ws layout (float offsets)
#define WS_PSUM   0u               // [25tc][16b][1536]
#define WS_PSQ    614400u          // [25tc][16b][1536]
#define WS_HCK    1228800u         // [128bk][256] head_ck (fp32)
#define WS_CKDOT  1261568u         // [128] sum_q head_ck*vck
#define WS_W1T    1261696u         // bf16 frag [8k][16qg][6kbg][64lane][8]
#define WS_HCQT   1458304u         // bf16 frag [128bk][12ag][8kb][64lane][8]
#define WS_PART   4604032u         // [128bk][32tile][192a] float4 (0,l,macc,m2acc)
#define WS_QVHQ   7749760u         // [8] sum_{q,a} query*vhq (b-independent)
#define WS_VCQS   7749768u         // [8][192] sum_q vcq[k,a,q]
// total = 7751304 floats ~= 31.0 MB

// k_main LDS (bytes):
//   khat: [0,32768)     [64t][256q] bf16, row 512B, XOR ((t&7)<<4)
//   Ab:   [0,16384)     [64t][96d] bf16, row 256B, XOR ((t&7)<<4)  (aliases khat;
//                        disjoint lifetime: Ab dead before khat written)
//   tbl4: [32768,36864) float4[256] = (hck, kpb, bn_scale, bn_shift)
//   lamred:[36864,37888) float[4][64]; row0 reused as lam table
#define LDS_BYTES 37888            // x4 blocks = 151552 <= 163840 -> 4 blocks/CU

typedef short bf16x8 __attribute__((ext_vector_type(8)));
typedef float f32x4  __attribute__((ext_vector_type(4)));

__device__ __forceinline__ float fast_tanh(float x) {
    return 1.f - 2.f / (__expf(2.f * x) + 1.f);
}
__device__ __forceinline__ float fast_sigmoid(float x) {
    return 1.f / (1.f + __expf(-x));
}
__device__ __forceinline__ short f2bf(float x) {   // RNE f32 -> bf16
    unsigned u = __builtin_bit_cast(unsigned, x);
    u += 0x7FFFu + ((u >> 16) & 1u);
    return (short)(u >> 16);
}

// ---------------- K1: fused pre-pass -----------------------------------------
// grid 456, block 384:
//   bid <400        : partial mean/sq sums over t-chunks (16b x 25tc x 80 rows)
//   bid 400..447    : k_proj_W fp32 [k][d][q] -> bf16 MFMA-frag layout
//   bid 448..455    : per-k qvhq scalar + vcq row-sums (b-independent hoists)
__global__ void k_pre(const float* __restrict__ ht,   const float* __restrict__ kpW,
                      const float* __restrict__ query, const float* __restrict__ vhq,
                      const float* __restrict__ vcq,  float* __restrict__ ws) {
    int bid = blockIdx.x, tid = threadIdx.x;
    if (bid < 400) {
        int tc = bid % 25;
        int b  = bid / 25;
        int c4 = tid * 4;
        const float* p = ht + ((size_t)b * TT + (size_t)tc * 80) * CC + c4;
        float4 s  = make_float4(0.f, 0.f, 0.f, 0.f);
        float4 s2 = make_float4(0.f, 0.f, 0.f, 0.f);
        #pragma unroll 8
        for (int i = 0; i < 80; ++i) {
            float4 v = *(const float4*)(p + (size_t)i * CC);
            s.x += v.x; s.y += v.y; s.z += v.z; s.w += v.w;
            s2.x = fmaf(v.x, v.x, s2.x); s2.y = fmaf(v.y, v.y, s2.y);
            s2.z = fmaf(v.z, v.z, s2.z); s2.w = fmaf(v.w, v.w, s2.w);
        }
        *(float4*)(ws + WS_PSUM + (size_t)(tc * BB + b) * CC + c4) = s;
        *(float4*)(ws + WS_PSQ  + (size_t)(tc * BB + b) * CC + c4) = s2;
    } else if (bid < 448) {
        if (tid < 256) {
            int kk  = (bid - 400) / 6, kbg = (bid - 400) % 6;
            int qg  = tid >> 4, lr = tid & 15;
            short* w1f = (short*)(ws + WS_W1T) + (size_t)kk * 49152;
            const float* src = kpW + (size_t)kk * DD * QQ;
            int q = qg * 16 + lr;
            #pragma unroll
            for (int lg = 0; lg < 4; ++lg) {
                bf16x8 v8;
                #pragma unroll
                for (int e = 0; e < 8; ++e) {
                    int d = kbg * 32 + lg * 8 + e;
                    v8[e] = f2bf(src[(size_t)d * QQ + q]);
                }
                *(bf16x8*)(w1f + ((qg * 6 + kbg) * 512 + (lg * 16 + lr) * 8)) = v8;
            }
        }
    } else {
        int kk = bid - 448;
        __shared__ float red6[6];
        float qv = 0.f;
        if (tid < 192) {
            int aa = tid;
            const float* qp = query + (size_t)kk * QQ * AA + aa;
            const float* hp = vhq + (size_t)kk * AA * QQ + (size_t)aa * QQ;
            const float* cp = vcq + (size_t)kk * AA * QQ + (size_t)aa * QQ;
            float vs = 0.f;
            #pragma unroll 4
            for (int qq = 0; qq < QQ; ++qq) {
                qv = fmaf(qp[(size_t)qq * AA], hp[qq], qv);
                vs += cp[qq];
            }
            ws[WS_VCQS + kk * 192 + aa] = vs;
        }
        #pragma unroll
        for (int off = 1; off < 64; off <<= 1) qv += __shfl_xor(qv, off);
        if ((tid & 63) == 0) red6[tid >> 6] = qv;
        __syncthreads();
        if (tid == 0)
            ws[WS_QVHQ + kk] = red6[0] + red6[1] + red6[2] + red6[3] + red6[4] + red6[5];
    }
}

// ---------------- K3: per-(b,k) prep (inlines finstats) ---------------------
__global__ void k_prep(const float* __restrict__ ukW,  const float* __restrict__ uq1W,
                       const float* __restrict__ uq1b, const float* __restrict__ uq2,
                       const float* __restrict__ query, const float* __restrict__ vck,
                       const float* __restrict__ bncg, const float* __restrict__ bncb,
                       const float* __restrict__ bncm, const float* __restrict__ bncv,
                       float* __restrict__ ws) {
    __shared__ float cv[384];
    __shared__ float cqh[QQ];
    __shared__ float red[256];
    __shared__ float stage[32 * 196];
    int bid = blockIdx.x;            // 128 = 16 b * 8 k
    int b = bid >> 3, k = bid & 7;
    int tid = threadIdx.x;

    // inline finstats: c = k*192 + tid  (tid<192)
    if (tid < 192) {
        float s = 0.f, s2 = 0.f;
        #pragma unroll 5
        for (int tc = 0; tc < 25; ++tc) {
            s  += ws[WS_PSUM + (size_t)(tc * BB + b) * CC + k * DD + tid];
            s2 += ws[WS_PSQ  + (size_t)(tc * BB + b) * CC + k * DD + tid];
        }
        float mean = s * (1.f / TT);
        float var  = (s2 - (float)TT * mean * mean) * (1.f / (TT - 1));
        cv[2 * tid]     = mean;
        cv[2 * tid + 1] = sqrtf(fmaxf(var, 0.f));
    }
    __syncthreads();

    int q = tid;  // 256 threads == Q
    const float* up = ukW + (size_t)k * 384 * QQ;
    float hck = 0.f, hckb = 0.f;
    #pragma unroll 4
    for (int l = 0; l < 384; l += 2) {     // two partial chains
        hck  = fmaf(cv[l],     up[l * QQ + q],       hck);
        hckb = fmaf(cv[l + 1], up[(l + 1) * QQ + q], hckb);
    }
    hck += hckb;
    ws[WS_HCK + (size_t)(b * NH + k) * QQ + q] = hck;

    const float* u1 = uq1W + (size_t)k * 384 * QQ;
    float cq = uq1b[k * QQ + q], cqb = 0.f;
    #pragma unroll 4
    for (int l = 0; l < 384; l += 2) {
        cq  = fmaf(cv[l],     u1[l * QQ + q],       cq);
        cqb = fmaf(cv[l + 1], u1[(l + 1) * QQ + q], cqb);
    }
    cq += cqb;
    cq = fmaxf(cq, 0.f);
    float sc = bncg[q] * rsqrtf(bncv[q] + 1e-5f);
    cq = fast_tanh(fmaf(cq - bncm[q], sc, bncb[q]));
    cqh[q] = cq;

    red[tid] = hck * vck[k * QQ + q];
    __syncthreads();
    #pragma unroll
    for (int off = 128; off > 0; off >>= 1) {
        if (tid < off) red[tid] += red[tid + off];
        __syncthreads();
    }
    if (tid == 0) ws[WS_CKDOT + b * NH + k] = red[0];
    __syncthreads();

    // cq2[a] = sum_m cqh[m] * u_q2[k,m,a]
    float c2 = 0.f;
    if (tid < AA) {
        const float* u2 = uq2 + (size_t)k * QQ * AA + tid;
        #pragma unroll 4
        for (int m = 0; m < QQ; ++m) c2 = fmaf(cqh[m], u2[m * AA], c2);
    }

    // lam_q = sigmoid(qvhq[k] + sum_a cq2[a]*vcqsum[k][a])
    red[tid] = (tid < AA) ? c2 * ws[WS_VCQS + k * 192 + tid] : 0.f;
    __syncthreads();
    #pragma unroll
    for (int off = 128; off > 0; off >>= 1) {
        if (tid < off) red[tid] += red[tid + off];
        __syncthreads();
    }
    float lq = fast_sigmoid(red[0] + ws[WS_QVHQ + k]);
    float one_lq = 1.f - lq;

    // head_cq -> bf16 MFMA-frag layout [ag][kb][lane][8] via LDS transpose
    {
        const float* qpan = query + (size_t)k * QQ * AA;
        short* hqf = (short*)(ws + WS_HCQT) + (size_t)(b * NH + k) * 49152;
        int ag = tid >> 4, lr = tid & 15;      // valid when tid<192
        for (int kb = 0; kb < 8; ++kb) {
            __syncthreads();   // stage (and prior red use) retired
            for (int i = tid; i < 32 * 192; i += 256) {
                int qt = i / 192, aa = i - qt * 192;
                stage[qt * 196 + aa] = qpan[(size_t)(kb * 32 + qt) * AA + aa];
            }
            __syncthreads();
            if (tid < AA) {
                #pragma unroll
                for (int lg = 0; lg < 4; ++lg) {
                    bf16x8 v8;
                    #pragma unroll
                    for (int e = 0; e < 8; ++e)
                        v8[e] = f2bf(fmaf(one_lq, stage[(lg * 8 + e) * 196 + tid], lq * c2));
                    *(bf16x8*)(hqf + ((ag * 8 + kb) * 64 + lg * 16 + lr) * 8) = v8;
                }
            }
        }
    }
}

// ---------------- K4: MFMA GEMM1 -> gate/BN/tanh -> MFMA GEMM2 -> softmax ---
__global__ __launch_bounds__(256, 4) void k_main(
        const float* __restrict__ ht,   const float* __restrict__ kpb,
        const float* __restrict__ vhk,  const float* __restrict__ qb_,
        const float* __restrict__ bnkg, const float* __restrict__ bnkb,
        const float* __restrict__ bnkm, const float* __restrict__ bnkv,
        float* __restrict__ ws) {
    extern __shared__ char lds[];
    float4* tbl4   = (float4*)(lds + 32768);   // (hck, kpb, bsc, bsh)
    float*  lamred = (float*)(lds + 36864);
    char*   Ab     = lds;                      // aliases khat (disjoint lifetime)

    int bid = blockIdx.x;         // 4096 = 128 bk * 32 tiles
    int bk = bid >> 5, tile = bid & 31;
    int b = bk >> 3, k = bk & 7;
    int t0 = tile * 64;
    int tid = threadIdx.x;
    int w   = tid >> 6;           // wave id (column-group owner)
    int lid = tid & 63;
    int lr = lid & 15, lg = lid >> 4;
    int nv = min(64, TT - t0);

    // ---- param table (per q) -------------------------------------------
    {
        int q = tid;
        float hckv = ws[WS_HCK + (size_t)bk * QQ + q];
        float kbv  = kpb[k * QQ + q];
        float bscv = bnkg[q] * rsqrtf(bnkv[q] + 1e-5f);
        float bshv = bnkb[q] - bnkm[q] * bscv;
        tbl4[q] = make_float4(hckv, kbv, bscv, bshv);
    }
    float ckd = ws[WS_CKDOT + bk];
    float vv[4];
    #pragma unroll
    for (int cc = 0; cc < 4; ++cc)
        vv[cc] = vhk[k * QQ + w * 64 + cc * 16 + lr];

    // ---- GEMM1: C1[64t][256q] = A[64][192] x W1[192][256] ---------------
    f32x4 acc1[4][4];
    #pragma unroll
    for (int tg = 0; tg < 4; ++tg)
        #pragma unroll
        for (int cc = 0; cc < 4; ++cc) acc1[tg][cc] = (f32x4){0.f, 0.f, 0.f, 0.f};

    const short* w1f = (const short*)(ws + WS_W1T) + (size_t)k * 49152;
    const int r_ = tid >> 2, cs = tid & 3;   // staging: 4 threads per t-row

    #pragma unroll
    for (int half = 0; half < 2; ++half) {
        __syncthreads();   // h1: all Ab reads of h0 retired (waves past MFMA section)
        {
            const float* src = ht + ((size_t)b * TT + t0 + r_) * CC + k * DD + half * 96;
            bool ok = (t0 + r_) < TT;
            #pragma unroll
            for (int u = 0; u < 6; ++u) {
                int c4 = cs * 24 + u * 4;
                float4 v = make_float4(0.f, 0.f, 0.f, 0.f);
                if (ok) v = *(const float4*)(src + c4);
                short4 s4;
                s4.x = f2bf(v.x); s4.y = f2bf(v.y); s4.z = f2bf(v.z); s4.w = f2bf(v.w);
                int byte = (r_ << 8) + (c4 << 1);
                byte ^= (r_ & 7) << 4;
                *(short4*)(Ab + byte) = s4;
            }
        }
        __syncthreads();
        #pragma unroll
        for (int kb = 0; kb < 3; ++kb) {
            bf16x8 af[4];
            #pragma unroll
            for (int tg = 0; tg < 4; ++tg) {
                int t = tg * 16 + lr;
                int byte = (t << 8) + ((kb * 32 + lg * 8) << 1);
                byte ^= (t & 7) << 4;
                af[tg] = *(const bf16x8*)(Ab + byte);
            }
            bf16x8 bf4[4];
            #pragma unroll
            for (int cc = 0; cc < 4; ++cc)
                bf4[cc] = *(const bf16x8*)(w1f + (((w * 4 + cc) * 6 + half * 3 + kb) << 9) + (lid << 3));
            #pragma unroll
            for (int cc = 0; cc < 4; ++cc)
                #pragma unroll
                for (int tg = 0; tg < 4; ++tg)
                    acc1[tg][cc] = __builtin_amdgcn_mfma_f32_16x16x32_bf16(af[tg], bf4[cc], acc1[tg][cc], 0, 0, 0);
        }
    }

    // ---- lam_k: cross-wave row-dot reduction ----------------------------
    {
        float rdp[4][4];
        #pragma unroll
        for (int tg = 0; tg < 4; ++tg)
            #pragma unroll
            for (int r = 0; r < 4; ++r) {
                float s = 0.f;
                #pragma unroll
                for (int cc = 0; cc < 4; ++cc) s = fmaf(acc1[tg][cc][r], vv[cc], s);
                #pragma unroll
                for (int off = 1; off < 16; off <<= 1) s += __shfl_xor(s, off);
                rdp[tg][r] = s;
            }
        if (lr == 0) {
            #pragma unroll
            for (int tg = 0; tg < 4; ++tg)
                #pragma unroll
                for (int r = 0; r < 4; ++r)
                    lamred[w * 64 + tg * 16 + lg * 4 + r] = rdp[tg][r];
        }
    }
    __syncthreads();
    if (tid < 64) {
        float s = lamred[tid] + lamred[64 + tid] + lamred[128 + tid] + lamred[192 + tid];
        lamred[tid] = fast_sigmoid(s + ckd);
    }
    __syncthreads();

    // ---- Phase 3: gate, bias, relu, BN, tanh -> khat bf16 ---------------
    {
        float lamv[4][4];
        #pragma unroll
        for (int tg = 0; tg < 4; ++tg)
            #pragma unroll
            for (int r = 0; r < 4; ++r)
                lamv[tg][r] = lamred[tg * 16 + lg * 4 + r];
        #pragma unroll
        for (int cc = 0; cc < 4; ++cc) {
            int q = w * 64 + cc * 16 + lr;
            float4 tv = tbl4[q];
            #pragma unroll
            for (int tg = 0; tg < 4; ++tg)
                #pragma unroll
                for (int r = 0; r < 4; ++r) {
                    float lam = lamv[tg][r];
                    float hk = (1.f - lam) * acc1[tg][cc][r] + lam * tv.x;
                    float x  = fmaxf(hk + tv.y, 0.f);
                    float kh = fast_tanh(fmaf(x, tv.z, tv.w));
                    int t = tg * 16 + lg * 4 + r;
                    int byte = (t << 9) + (q << 1);
                    byte ^= (t & 7) << 4;
                    *(short*)(lds + byte) = f2bf(kh);
                }
        }
    }
    __syncthreads();   // khat fully written (cross-wave reads follow)

    // ---- GEMM2: S[64t][192a] = khat[64][256] x hcq[256][192] ------------
    f32x4 acc2[4][3];
    #pragma unroll
    for (int tg = 0; tg < 4; ++tg)
        #pragma unroll
        for (int cc = 0; cc < 3; ++cc) acc2[tg][cc] = (f32x4){0.f, 0.f, 0.f, 0.f};

    const short* hqf = (const short*)(ws + WS_HCQT) + (size_t)bk * 49152;
    #pragma unroll
    for (int kb = 0; kb < 8; ++kb) {
        bf16x8 kf[4];
        #pragma unroll
        for (int tg = 0; tg < 4; ++tg) {
            int t = tg * 16 + lr;
            int byte = (t << 9) + ((kb * 32 + lg * 8) << 1);
            byte ^= (t & 7) << 4;
            kf[tg] = *(const bf16x8*)(lds + byte);
        }
        bf16x8 bf3[3];
        #pragma unroll
        for (int cc = 0; cc < 3; ++cc)
            bf3[cc] = *(const bf16x8*)(hqf + (((w * 3 + cc) * 8 + kb) << 9) + (lid << 3));
        #pragma unroll
        for (int cc = 0; cc < 3; ++cc)
            #pragma unroll
            for (int tg = 0; tg < 4; ++tg)
                acc2[tg][cc] = __builtin_amdgcn_mfma_f32_16x16x32_bf16(kf[tg], bf3[cc], acc2[tg][cc], 0, 0, 0);
    }

    // ---- Phase 5: in-register softmax partials + lg-shuffle reduce ------
    #pragma unroll
    for (int cc = 0; cc < 3; ++cc) {
        int a = w * 48 + cc * 16 + lr;
        float qbv = qb_[k * AA + a];
        const float* vp = ht + ((size_t)b * TT + t0) * CC + k * DD + a;
        float lsum = 0.f, mac = 0.f, m2 = 0.f;
        if (nv == 64) {
            #pragma unroll
            for (int tg = 0; tg < 4; ++tg)
                #pragma unroll
                for (int r = 0; r < 4; ++r) {
                    int t = tg * 16 + lg * 4 + r;
                    float s = fminf(fmaf(acc2[tg][cc][r], 0.0625f, qbv), 30.f);
                    float e = __expf(s);
                    float v = vp[(size_t)t * CC];
                    float t1 = e * v;
                    lsum += e;
                    mac  += t1;
                    m2    = fmaf(t1, v, m2);
                }
        } else {
            #pragma unroll
            for (int tg = 0; tg < 4; ++tg)
                #pragma unroll
                for (int r = 0; r < 4; ++r) {
                    int t = tg * 16 + lg * 4 + r;
                    if (t < nv) {
                        float s = fminf(fmaf(acc2[tg][cc][r], 0.0625f, qbv), 30.f);
                        float e = __expf(s);
                        float v = vp[(size_t)t * CC];
                        float t1 = e * v;
                        lsum += e;
                        mac  += t1;
                        m2    = fmaf(t1, v, m2);
                    }
                }
        }
        lsum += __shfl_xor(lsum, 16); lsum += __shfl_xor(lsum, 32);
        mac  += __shfl_xor(mac, 16);  mac  += __shfl_xor(mac, 32);
        m2   += __shfl_xor(m2, 16);   m2   += __shfl_xor(m2, 32);
        if (lg == 0)
            ((float4*)(ws + WS_PART))[(size_t)(bk * 32 + tile) * AA + a] =
                make_float4(0.f, lsum, mac, m2);
    }
}

// ---------------- K5: merge tile partials, emit mu / rh ---------------------
__global__ void k_merge(const float* __restrict__ ws, float* __restrict__ out) {
    int bk = blockIdx.x;             // 128
    int b = bk >> 3, k = bk & 7;
    int a = threadIdx.x;             // 192
    const float4* part = (const float4*)(ws + WS_PART) + (size_t)bk * 32 * AA + a;
    float L = 0.f, MU = 0.f, M2 = 0.f;
    #pragma unroll 8
    for (int ti = 0; ti < 32; ++ti) {
        float4 p = part[(size_t)ti * AA];
        L += p.y; MU += p.z; M2 += p.w;
    }
    MU /= L;
    M2 /= L;
    float rh = sqrtf(fmaxf(M2 - MU * MU, 1e-9f));
    out[(size_t)b * 3072 + k * DD + a]      = MU;
    out[(size_t)b * 3072 + CC + k * DD + a] = rh;
}

// ---------------------------------------------------------------------------
extern "C" void kernel_launch(void* const* d_in, const int* in_sizes, int n_in,
                              void* d_out, int out_size, void* d_ws, size_t ws_size,
                              hipStream_t stream) {
    const float* ht    = (const float*)d_in[0];
    const float* kpW   = (const float*)d_in[1];
    const float* query = (const float*)d_in[2];
    const float* ukW   = (const float*)d_in[3];
    const float* uq1W  = (const float*)d_in[4];
    const float* uq2   = (const float*)d_in[5];
    const float* vhq   = (const float*)d_in[6];
    const float* vhk   = (const float*)d_in[7];
    const float* vcq   = (const float*)d_in[8];
    const float* vck   = (const float*)d_in[9];
    const float* kpb   = (const float*)d_in[10];
    const float* qb    = (const float*)d_in[11];
    const float* uq1b  = (const float*)d_in[12];
    const float* bncg  = (const float*)d_in[13];
    const float* bncb  = (const float*)d_in[14];
    const float* bncm  = (const float*)d_in[15];
    const float* bncv  = (const float*)d_in[16];
    const float* bnkg  = (const float*)d_in[17];
    const float* bnkb  = (const float*)d_in[18];
    const float* bnkm  = (const float*)d_in[19];
    const float* bnkv  = (const float*)d_in[20];
    float* ws  = (float*)d_ws;
    float* out = (float*)d_out;

    hipFuncSetAttribute(reinterpret_cast<const void*>(k_main),
                        hipFuncAttributeMaxDynamicSharedMemorySize, LDS_BYTES);

    k_pre  <<<456, 384, 0, stream>>>(ht, kpW, query, vhq, vcq, ws);
    k_prep <<<128, 256, 0, stream>>>(ukW, uq1W, uq1b, uq2, query, vck,
                                     bncg, bncb, bncm, bncv, ws);
    k_main <<<4096, 256, LDS_BYTES, stream>>>(ht, kpb, vhk, qb,
                                              bnkg, bnkb, bnkm, bnkv, ws);
    k_merge<<<128, 192, 0, stream>>>(ws, out);
}